// Round 4
// baseline (218.906 us; speedup 1.0000x reference)
//
#include <hip/hip_runtime.h>

#define SLOPE 0.1f
#define NEG_INF_F (-9000000000000000.0f)

typedef int   iv4 __attribute__((ext_vector_type(4)));
typedef float fv4 __attribute__((ext_vector_type(4)));

// Problem constants: S=8, N=2048, IN_F=256, OUT_F=64
// rows = S*N = 16384 (flat row index fr = s*2048 + i)

// ---------------------------------------------------------------------------
// Kernel 0: transpose W_w [64][256] -> wT [256][64] (k-major).
// ---------------------------------------------------------------------------
__global__ void k_wt(const float* __restrict__ W, float* __restrict__ wT) {
    int idx = blockIdx.x * 256 + threadIdx.x;   // 0..16383
    int k = idx >> 6, f = idx & 63;
    wT[idx] = W[f * 256 + k];                   // wT[k][f] = W[f][k]
}

// ---------------------------------------------------------------------------
// Kernel A: h = inDoc @ W^T + b (f32), fused scores si/sj.
// Block = 256 threads, 64-row x 64-f tile, K-chunks of 32.
// ---------------------------------------------------------------------------
__global__ __launch_bounds__(256) void k_h(
    const float* __restrict__ inDoc, const float* __restrict__ wT,
    const float* __restrict__ Wb, const float* __restrict__ aw,
    float* __restrict__ h, float* __restrict__ si, float* __restrict__ sj)
{
    __shared__ float wTl[32 * 64];      // [k][f], 8 KB
    __shared__ float inl[64][36];       // [r][k], pad +4 keeps 16B align, 9 KB
    const int t  = threadIdx.x;
    const int R0 = blockIdx.x * 64;
    const int fq = t & 15, rq = t >> 4;
    const int f0 = fq << 2;

    float acc[4][4];
#pragma unroll
    for (int r = 0; r < 4; ++r)
#pragma unroll
        for (int c = 0; c < 4; ++c) acc[r][c] = 0.f;

    for (int kc = 0; kc < 8; ++kc) {
        __syncthreads();
        {   // stage wT chunk [32][64] -- k-major already, linear copy
            const float4* src = (const float4*)(wT + kc * 2048);
            float4 a = src[t * 2], b = src[t * 2 + 1];
            ((float4*)wTl)[t * 2]     = a;
            ((float4*)wTl)[t * 2 + 1] = b;
        }
        {   // stage inDoc chunk [64 rows][32 k]
            int r = t >> 2, q = t & 3;
            const float* src = inDoc + (size_t)(R0 + r) * 256 + kc * 32 + q * 8;
            float4 a = *(const float4*)src;
            float4 b = *(const float4*)(src + 4);
            *(float4*)&inl[r][q * 8]     = a;
            *(float4*)&inl[r][q * 8 + 4] = b;
        }
        __syncthreads();
#pragma unroll
        for (int k4 = 0; k4 < 8; ++k4) {
            const int k0 = k4 << 2;
            float w[4][4];
#pragma unroll
            for (int j = 0; j < 4; ++j) {
                float4 wv = *(const float4*)&wTl[(k0 + j) * 64 + f0];
                w[j][0] = wv.x; w[j][1] = wv.y; w[j][2] = wv.z; w[j][3] = wv.w;
            }
#pragma unroll
            for (int r = 0; r < 4; ++r) {
                float4 av = *(const float4*)&inl[rq * 4 + r][k0];
                float a[4] = {av.x, av.y, av.z, av.w};
#pragma unroll
                for (int j = 0; j < 4; ++j)
#pragma unroll
                    for (int c = 0; c < 4; ++c)
                        acc[r][c] = fmaf(a[j], w[j][c], acc[r][c]);
            }
        }
    }

    // bias + scores
    float bw[4], a1[4], a2[4];
#pragma unroll
    for (int c = 0; c < 4; ++c) {
        bw[c] = Wb[f0 + c];
        a1[c] = aw[f0 + c];
        a2[c] = aw[64 + f0 + c];
    }
    float sip[4], sjp[4];
#pragma unroll
    for (int r = 0; r < 4; ++r) {
#pragma unroll
        for (int c = 0; c < 4; ++c) acc[r][c] += bw[c];
        float x = 0.f, y = 0.f;
#pragma unroll
        for (int c = 0; c < 4; ++c) {
            x = fmaf(acc[r][c], a1[c], x);
            y = fmaf(acc[r][c], a2[c], y);
        }
        sip[r] = x; sjp[r] = y;
    }
#pragma unroll
    for (int m = 1; m <= 8; m <<= 1) {
#pragma unroll
        for (int r = 0; r < 4; ++r) {
            sip[r] += __shfl_xor(sip[r], m, 64);
            sjp[r] += __shfl_xor(sjp[r], m, 64);
        }
    }
    const int rowbase = R0 + rq * 4;
#pragma unroll
    for (int r = 0; r < 4; ++r) {
        float4 hv = make_float4(acc[r][0], acc[r][1], acc[r][2], acc[r][3]);
        *(float4*)&h[(size_t)(rowbase + r) * 64 + f0] = hv;
    }
    if (fq == 0) {
#pragma unroll
        for (int r = 0; r < 4; ++r) {
            si[rowbase + r] = sip[r];
            sj[rowbase + r] = sjp[r];
        }
    }
}

// ---------------------------------------------------------------------------
// Kernel B: 8 rows/block. Phase 1: wave-per-row register softmax.
// Phase 2: PV with broadcast LDS p + coalesced h reads.
// ---------------------------------------------------------------------------
__global__ __launch_bounds__(256) void k_att(
    const int* __restrict__ adj, const float* __restrict__ h,
    const float* __restrict__ si, const float* __restrict__ sj,
    const float* __restrict__ ab_p,
    float* __restrict__ out_h, float* __restrict__ out_att)
{
    __shared__ float pL[8][2048];       // 64 KB, normalized att rows
    const int t    = threadIdx.x;
    const int lane = t & 63, wv = t >> 6;
    const int i0   = blockIdx.x * 8;    // flat row base
    const int s    = i0 >> 11;
    const float ab = ab_p[0];
    const float* sjb = sj + (size_t)s * 2048;

    // ---- phase 1: softmax rows ----
    for (int rr = 0; rr < 2; ++rr) {
        const int r  = wv + rr * 4;
        const int fr = i0 + r;
        const float sival = si[fr] + ab;
        const int* arow = adj + (size_t)fr * 2048;
        float v[32];
#pragma unroll
        for (int c = 0; c < 8; ++c) {
            const int j = c * 256 + lane * 4;
            iv4  m  = __builtin_nontemporal_load((const iv4*)(arow + j));
            float4 sv = *(const float4*)(sjb + j);
            float x;
            x = sival + sv.x; x = fmaxf(x, SLOPE * x);
            v[c*4+0] = (m.x == 0 || m.x == -1) ? NEG_INF_F : x;
            x = sival + sv.y; x = fmaxf(x, SLOPE * x);
            v[c*4+1] = (m.y == 0 || m.y == -1) ? NEG_INF_F : x;
            x = sival + sv.z; x = fmaxf(x, SLOPE * x);
            v[c*4+2] = (m.z == 0 || m.z == -1) ? NEG_INF_F : x;
            x = sival + sv.w; x = fmaxf(x, SLOPE * x);
            v[c*4+3] = (m.w == 0 || m.w == -1) ? NEG_INF_F : x;
        }
        float mx = v[0];
#pragma unroll
        for (int q = 1; q < 32; ++q) mx = fmaxf(mx, v[q]);
#pragma unroll
        for (int m2 = 1; m2 < 64; m2 <<= 1) mx = fmaxf(mx, __shfl_xor(mx, m2, 64));
        float sum = 0.f;
#pragma unroll
        for (int q = 0; q < 32; ++q) { v[q] = __expf(v[q] - mx); sum += v[q]; }
#pragma unroll
        for (int m2 = 1; m2 < 64; m2 <<= 1) sum += __shfl_xor(sum, m2, 64);
        const float inv = 1.0f / sum;

        float* attrow = out_att + (size_t)fr * 2048;
#pragma unroll
        for (int c = 0; c < 8; ++c) {
            const int j = c * 256 + lane * 4;
            fv4 pv;
            pv.x = v[c*4+0] * inv; pv.y = v[c*4+1] * inv;
            pv.z = v[c*4+2] * inv; pv.w = v[c*4+3] * inv;
            __builtin_nontemporal_store(pv, (fv4*)(attrow + j));
            *(fv4*)&pL[r][j] = pv;
        }
    }
    __syncthreads();

    // ---- phase 2: PV ----
    const int f = lane;
    const float* hb = h + (size_t)s * 2048 * 64 + f;
    float acc0 = 0.f, acc1 = 0.f;
#pragma unroll 4
    for (int j0 = 0; j0 < 2048; j0 += 4) {
        float4 p0 = *(const float4*)&pL[wv][j0];
        float4 p1 = *(const float4*)&pL[wv + 4][j0];
        float h0 = hb[(j0 + 0) * 64];
        float h1 = hb[(j0 + 1) * 64];
        float h2 = hb[(j0 + 2) * 64];
        float h3 = hb[(j0 + 3) * 64];
        acc0 = fmaf(p0.x, h0, acc0); acc0 = fmaf(p0.y, h1, acc0);
        acc0 = fmaf(p0.z, h2, acc0); acc0 = fmaf(p0.w, h3, acc0);
        acc1 = fmaf(p1.x, h0, acc1); acc1 = fmaf(p1.y, h1, acc1);
        acc1 = fmaf(p1.z, h2, acc1); acc1 = fmaf(p1.w, h3, acc1);
    }
    float o0 = fmaxf(acc0, SLOPE * acc0);
    float o1 = fmaxf(acc1, SLOPE * acc1);
    out_h[(size_t)(i0 + wv) * 64 + f]     = o0;
    out_h[(size_t)(i0 + wv + 4) * 64 + f] = o1;
}

// ---------------------------------------------------------------------------
extern "C" void kernel_launch(void* const* d_in, const int* in_sizes, int n_in,
                              void* d_out, int out_size, void* d_ws, size_t ws_size,
                              hipStream_t stream) {
    const float* inDoc = (const float*)d_in[0];   // [8][2048][256]
    const int*   adj   = (const int*)d_in[1];     // [8][2048][2048][1]
    const float* W_w   = (const float*)d_in[2];   // [64][256]
    const float* W_b   = (const float*)d_in[3];   // [64]
    const float* a_w   = (const float*)d_in[4];   // [1][128]
    const float* a_b   = (const float*)d_in[5];   // [1]

    float* out     = (float*)d_out;
    float* out_h   = out;                          // 16384*64
    float* out_att = out + (size_t)16384 * 64;     // 8*2048*2048

    float* ws = (float*)d_ws;
    float* wT = ws;                                // 256*64
    float* h  = wT + 16384;                        // 16384*64
    float* si = h + (size_t)16384 * 64;            // 16384
    float* sj = si + 16384;                        // 16384

    k_wt <<<64,   256, 0, stream>>>(W_w, wT);
    k_h  <<<256,  256, 0, stream>>>(inDoc, wT, W_b, a_w, h, si, sj);
    k_att<<<2048, 256, 0, stream>>>(adj, h, si, sj, a_b, out_h, out_att);
}

// Round 8
// 102.171 us; speedup vs baseline: 2.1426x; 2.1426x over previous
//
#include <hip/hip_runtime.h>

#define SLOPE 0.1f
#define NEG_INF_F (-9000000000000000.0f)

typedef int            iv4    __attribute__((ext_vector_type(4)));
typedef float          fv4    __attribute__((ext_vector_type(4)));
typedef unsigned short u16;
typedef u16            u16v4  __attribute__((ext_vector_type(4)));
typedef __bf16         bf16x8 __attribute__((ext_vector_type(8)));

static __device__ __forceinline__ u16 f2bf(float x) {
    union { float f; unsigned u; } v; v.f = x;
    unsigned r = v.u + 0x7fffu + ((v.u >> 16) & 1u);   // round-nearest-even
    return (u16)(r >> 16);
}

// Problem constants: S=8, N=2048, IN_F=256, OUT_F=64; rows = 16384.

// ---------------------------------------------------------------------------
// Kernel 0: transpose W_w [64][256] -> wT [256][64] (k-major).
// ---------------------------------------------------------------------------
__global__ void k_wt(const float* __restrict__ W, float* __restrict__ wT) {
    int idx = blockIdx.x * 256 + threadIdx.x;
    int k = idx >> 6, f = idx & 63;
    wT[idx] = W[f * 256 + k];
}

// ---------------------------------------------------------------------------
// Kernel A: h = inDoc @ W^T + b (f32). Outputs: hT bf16 [s][f][i] (PV operand),
// si/sj score vectors. 64-row x 64-f tile per block.
// ---------------------------------------------------------------------------
__global__ __launch_bounds__(256) void k_h(
    const float* __restrict__ inDoc, const float* __restrict__ wT,
    const float* __restrict__ Wb, const float* __restrict__ aw,
    u16* __restrict__ hT, float* __restrict__ si, float* __restrict__ sj)
{
    __shared__ float wTl[32 * 64];
    __shared__ float inl[64][36];
    const int t  = threadIdx.x;
    const int R0 = blockIdx.x * 64;
    const int fq = t & 15, rq = t >> 4;
    const int f0 = fq << 2;

    float acc[4][4];
#pragma unroll
    for (int r = 0; r < 4; ++r)
#pragma unroll
        for (int c = 0; c < 4; ++c) acc[r][c] = 0.f;

    for (int kc = 0; kc < 8; ++kc) {
        __syncthreads();
        {
            const float4* src = (const float4*)(wT + kc * 2048);
            float4 a = src[t * 2], b = src[t * 2 + 1];
            ((float4*)wTl)[t * 2]     = a;
            ((float4*)wTl)[t * 2 + 1] = b;
        }
        {
            int r = t >> 2, q = t & 3;
            const float* src = inDoc + (size_t)(R0 + r) * 256 + kc * 32 + q * 8;
            float4 a = *(const float4*)src;
            float4 b = *(const float4*)(src + 4);
            *(float4*)&inl[r][q * 8]     = a;
            *(float4*)&inl[r][q * 8 + 4] = b;
        }
        __syncthreads();
#pragma unroll
        for (int k4 = 0; k4 < 8; ++k4) {
            const int k0 = k4 << 2;
            float w[4][4];
#pragma unroll
            for (int j = 0; j < 4; ++j) {
                float4 wv = *(const float4*)&wTl[(k0 + j) * 64 + f0];
                w[j][0] = wv.x; w[j][1] = wv.y; w[j][2] = wv.z; w[j][3] = wv.w;
            }
#pragma unroll
            for (int r = 0; r < 4; ++r) {
                float4 av = *(const float4*)&inl[rq * 4 + r][k0];
                float a[4] = {av.x, av.y, av.z, av.w};
#pragma unroll
                for (int j = 0; j < 4; ++j)
#pragma unroll
                    for (int c = 0; c < 4; ++c)
                        acc[r][c] = fmaf(a[j], w[j][c], acc[r][c]);
            }
        }
    }

    float bw[4], a1[4], a2[4];
#pragma unroll
    for (int c = 0; c < 4; ++c) {
        bw[c] = Wb[f0 + c];
        a1[c] = aw[f0 + c];
        a2[c] = aw[64 + f0 + c];
    }
    float sip[4], sjp[4];
#pragma unroll
    for (int r = 0; r < 4; ++r) {
#pragma unroll
        for (int c = 0; c < 4; ++c) acc[r][c] += bw[c];
        float x = 0.f, y = 0.f;
#pragma unroll
        for (int c = 0; c < 4; ++c) {
            x = fmaf(acc[r][c], a1[c], x);
            y = fmaf(acc[r][c], a2[c], y);
        }
        sip[r] = x; sjp[r] = y;
    }
#pragma unroll
    for (int m = 1; m <= 8; m <<= 1) {
#pragma unroll
        for (int r = 0; r < 4; ++r) {
            sip[r] += __shfl_xor(sip[r], m, 64);
            sjp[r] += __shfl_xor(sjp[r], m, 64);
        }
    }
    const int rowbase = R0 + rq * 4;
    const int sR = rowbase >> 11;
    const int il = rowbase & 2047;
    u16* hTp = hT + (size_t)sR * 131072;   // [64][2048] per s
#pragma unroll
    for (int r = 0; r < 4; ++r)
#pragma unroll
        for (int c = 0; c < 4; ++c)
            hTp[(size_t)(f0 + c) * 2048 + il + r] = f2bf(acc[r][c]);
    if (fq == 0) {
#pragma unroll
        for (int r = 0; r < 4; ++r) {
            si[rowbase + r] = sip[r];
            sj[rowbase + r] = sjp[r];
        }
    }
}

// ---------------------------------------------------------------------------
// Kernel B: 16 rows/block (4 waves x 4 rows). Phase 1: wave-register softmax,
// f32 att out + bf16 p into swizzled LDS. Phase 2: MFMA PV:
//   C[f][i] = sum_k hT[f][k] * p[i][k]  via mfma_f32_16x16x32_bf16.
// ---------------------------------------------------------------------------
__global__ __launch_bounds__(256) void k_att(
    const int* __restrict__ adj, const u16* __restrict__ hT,
    const float* __restrict__ si, const float* __restrict__ sj,
    const float* __restrict__ ab_p,
    float* __restrict__ out_h, float* __restrict__ out_att)
{
    __shared__ __align__(16) u16 pB[16 * 2048];   // 64 KB bf16, XOR-swizzled
    const int t    = threadIdx.x;
    const int lane = t & 63, wv = t >> 6;
    const int i0   = blockIdx.x * 16;
    const int s    = i0 >> 11;
    const float ab = ab_p[0];
    const float* sjb = sj + (size_t)s * 2048;

    // sj is shared by all rows of this s -- hoist (32 floats/lane)
    fv4 sv[8];
#pragma unroll
    for (int c = 0; c < 8; ++c)
        sv[c] = *(const fv4*)(sjb + c * 256 + lane * 4);

    // ---- phase 1: 4 rows per wave ----
    for (int rr = 0; rr < 4; ++rr) {
        const int r  = wv * 4 + rr;
        const int fr = i0 + r;
        const float sival = si[fr] + ab;
        const int* arow = adj + (size_t)fr * 2048;
        float v[32];
#pragma unroll
        for (int c = 0; c < 8; ++c) {
            const int j = c * 256 + lane * 4;
            iv4 m = __builtin_nontemporal_load((const iv4*)(arow + j));
            float x;
            x = sival + sv[c].x; x = fmaxf(x, SLOPE * x);
            v[c*4+0] = (m.x == 0 || m.x == -1) ? NEG_INF_F : x;
            x = sival + sv[c].y; x = fmaxf(x, SLOPE * x);
            v[c*4+1] = (m.y == 0 || m.y == -1) ? NEG_INF_F : x;
            x = sival + sv[c].z; x = fmaxf(x, SLOPE * x);
            v[c*4+2] = (m.z == 0 || m.z == -1) ? NEG_INF_F : x;
            x = sival + sv[c].w; x = fmaxf(x, SLOPE * x);
            v[c*4+3] = (m.w == 0 || m.w == -1) ? NEG_INF_F : x;
        }
        float mx = v[0];
#pragma unroll
        for (int q = 1; q < 32; ++q) mx = fmaxf(mx, v[q]);
#pragma unroll
        for (int m2 = 1; m2 < 64; m2 <<= 1) mx = fmaxf(mx, __shfl_xor(mx, m2, 64));
        float sum = 0.f;
#pragma unroll
        for (int q = 0; q < 32; ++q) { v[q] = __expf(v[q] - mx); sum += v[q]; }
#pragma unroll
        for (int m2 = 1; m2 < 64; m2 <<= 1) sum += __shfl_xor(sum, m2, 64);
        const float inv = 1.0f / sum;

        float* attrow = out_att + (size_t)fr * 2048;
        const unsigned swz = (unsigned)(r & 7) << 4;
#pragma unroll
        for (int c = 0; c < 8; ++c) {
            const int j = c * 256 + lane * 4;
            fv4 pv;
            pv.x = v[c*4+0] * inv; pv.y = v[c*4+1] * inv;
            pv.z = v[c*4+2] * inv; pv.w = v[c*4+3] * inv;
            __builtin_nontemporal_store(pv, (fv4*)(attrow + j));
            u16v4 pk;
            pk.x = f2bf(pv.x); pk.y = f2bf(pv.y);
            pk.z = f2bf(pv.z); pk.w = f2bf(pv.w);
            unsigned byte = ((unsigned)(r * 4096 + j * 2)) ^ swz;
            *(u16v4*)((char*)pB + byte) = pk;
        }
    }
    __syncthreads();

    // ---- phase 2: MFMA PV ----
    // Wave wv computes C tile: f in [wv*16, wv*16+16), i in [i0, i0+16), K=2048.
    // A-frag: hT[f0 + (lane&15)][k0 + (lane>>4)*8 + e]  (16B global, bf16)
    // B-frag: p[lane&15][k0 + (lane>>4)*8 + e]          (16B LDS, swizzled)
    const int m16   = lane & 15;
    const int klane = lane >> 4;
    const unsigned sw = (unsigned)(lane & 7) << 4;
    const __bf16* hTs = (const __bf16*)hT + (size_t)s * 131072
                      + (size_t)(wv * 16 + m16) * 2048 + klane * 8;
    const unsigned bbase = (unsigned)(m16 * 4096 + klane * 16);
    fv4 acc = {0.f, 0.f, 0.f, 0.f};
#pragma unroll 4
    for (int k0 = 0; k0 < 2048; k0 += 32) {
        bf16x8 a = *(const bf16x8*)(hTs + k0);
        unsigned byte = (bbase + (unsigned)(k0 * 2)) ^ sw;
        bf16x8 b = *(const bf16x8*)((const char*)pB + byte);
        acc = __builtin_amdgcn_mfma_f32_16x16x32_bf16(a, b, acc, 0, 0, 0);
    }
    // C/D layout: col = lane&15 -> i, row = klane*4 + reg -> f
    const int orow = i0 + m16;
    float* op = out_h + (size_t)orow * 64 + wv * 16 + klane * 4;
    fv4 o;
    o.x = fmaxf(acc.x, SLOPE * acc.x);
    o.y = fmaxf(acc.y, SLOPE * acc.y);
    o.z = fmaxf(acc.z, SLOPE * acc.z);
    o.w = fmaxf(acc.w, SLOPE * acc.w);
    *(fv4*)op = o;
}

// ---------------------------------------------------------------------------
extern "C" void kernel_launch(void* const* d_in, const int* in_sizes, int n_in,
                              void* d_out, int out_size, void* d_ws, size_t ws_size,
                              hipStream_t stream) {
    const float* inDoc = (const float*)d_in[0];   // [8][2048][256]
    const int*   adj   = (const int*)d_in[1];     // [8][2048][2048][1]
    const float* W_w   = (const float*)d_in[2];   // [64][256]
    const float* W_b   = (const float*)d_in[3];   // [64]
    const float* a_w   = (const float*)d_in[4];   // [1][128]
    const float* a_b   = (const float*)d_in[5];   // [1]

    float* out     = (float*)d_out;
    float* out_h   = out;                          // 16384*64
    float* out_att = out + (size_t)16384 * 64;     // 8*2048*2048

    float* ws = (float*)d_ws;
    float* wT = ws;                                // 16384 f32
    u16*   hT = (u16*)(ws + 16384);                // 8*64*2048 bf16 = 2 MB
    float* si = (float*)(hT + (size_t)8 * 64 * 2048);
    float* sj = si + 16384;

    k_wt <<<64,   256, 0, stream>>>(W_w, wT);
    k_h  <<<256,  256, 0, stream>>>(inDoc, wT, W_b, a_w, hT, si, sj);
    k_att<<<1024, 256, 0, stream>>>(adj, hT, si, sj, a_b, out_h, out_att);
}

// Round 9
// 100.767 us; speedup vs baseline: 2.1724x; 1.0139x over previous
//
#include <hip/hip_runtime.h>

#define SLOPE 0.1f
#define NEG_INF_F (-9000000000000000.0f)

typedef int            iv4    __attribute__((ext_vector_type(4)));
typedef float          fv4    __attribute__((ext_vector_type(4)));
typedef unsigned short u16;
typedef u16            u16v4  __attribute__((ext_vector_type(4)));
typedef __bf16         bf16x8 __attribute__((ext_vector_type(8)));

static __device__ __forceinline__ u16 f2bf(float x) {
    union { float f; unsigned u; } v; v.f = x;
    unsigned r = v.u + 0x7fffu + ((v.u >> 16) & 1u);   // round-nearest-even
    return (u16)(r >> 16);
}

// Problem constants: S=8, N=2048, IN_F=256, OUT_F=64; rows = 16384.

// ---------------------------------------------------------------------------
// Kernel 0: transpose W_w [64][256] -> wT [256][64] (k-major).
// ---------------------------------------------------------------------------
__global__ void k_wt(const float* __restrict__ W, float* __restrict__ wT) {
    int idx = blockIdx.x * 256 + threadIdx.x;
    int k = idx >> 6, f = idx & 63;
    wT[idx] = W[f * 256 + k];
}

// ---------------------------------------------------------------------------
// Kernel A: h = inDoc @ W^T + b (f32). Outputs: hT bf16 [s][f][i] (PV operand),
// si/sj score vectors. 32-row x 64-f tile per block (512 blocks = 2/CU).
// ---------------------------------------------------------------------------
__global__ __launch_bounds__(256) void k_h(
    const float* __restrict__ inDoc, const float* __restrict__ wT,
    const float* __restrict__ Wb, const float* __restrict__ aw,
    u16* __restrict__ hT, float* __restrict__ si, float* __restrict__ sj)
{
    __shared__ float wTl[32 * 64];      // [k][f], 8 KB
    __shared__ float inl[32][36];       // [r][k], 4.6 KB
    const int t  = threadIdx.x;
    const int R0 = blockIdx.x * 32;
    const int fq = t & 15, rq = t >> 4;
    const int f0 = fq << 2;

    float acc[2][4];
#pragma unroll
    for (int r = 0; r < 2; ++r)
#pragma unroll
        for (int c = 0; c < 4; ++c) acc[r][c] = 0.f;

    for (int kc = 0; kc < 8; ++kc) {
        __syncthreads();
        {   // stage wT chunk [32][64]
            const float4* src = (const float4*)(wT + kc * 2048);
            float4 a = src[t * 2], b = src[t * 2 + 1];
            ((float4*)wTl)[t * 2]     = a;
            ((float4*)wTl)[t * 2 + 1] = b;
        }
        {   // stage inDoc chunk [32 rows][32 k]
            int r = t >> 3, q = t & 7;
            const float* src = inDoc + (size_t)(R0 + r) * 256 + kc * 32 + q * 4;
            *(float4*)&inl[r][q * 4] = *(const float4*)src;
        }
        __syncthreads();
#pragma unroll
        for (int k4 = 0; k4 < 8; ++k4) {
            const int k0 = k4 << 2;
            float w[4][4];
#pragma unroll
            for (int j = 0; j < 4; ++j) {
                float4 wv = *(const float4*)&wTl[(k0 + j) * 64 + f0];
                w[j][0] = wv.x; w[j][1] = wv.y; w[j][2] = wv.z; w[j][3] = wv.w;
            }
#pragma unroll
            for (int r = 0; r < 2; ++r) {
                float4 av = *(const float4*)&inl[rq * 2 + r][k0];
                float a[4] = {av.x, av.y, av.z, av.w};
#pragma unroll
                for (int j = 0; j < 4; ++j)
#pragma unroll
                    for (int c = 0; c < 4; ++c)
                        acc[r][c] = fmaf(a[j], w[j][c], acc[r][c]);
            }
        }
    }

    float bw[4], a1[4], a2[4];
#pragma unroll
    for (int c = 0; c < 4; ++c) {
        bw[c] = Wb[f0 + c];
        a1[c] = aw[f0 + c];
        a2[c] = aw[64 + f0 + c];
    }
    float sip[2], sjp[2];
#pragma unroll
    for (int r = 0; r < 2; ++r) {
#pragma unroll
        for (int c = 0; c < 4; ++c) acc[r][c] += bw[c];
        float x = 0.f, y = 0.f;
#pragma unroll
        for (int c = 0; c < 4; ++c) {
            x = fmaf(acc[r][c], a1[c], x);
            y = fmaf(acc[r][c], a2[c], y);
        }
        sip[r] = x; sjp[r] = y;
    }
#pragma unroll
    for (int m = 1; m <= 8; m <<= 1) {
#pragma unroll
        for (int r = 0; r < 2; ++r) {
            sip[r] += __shfl_xor(sip[r], m, 64);
            sjp[r] += __shfl_xor(sjp[r], m, 64);
        }
    }
    const int rowbase = R0 + rq * 2;
    const int sR = rowbase >> 11;
    const int il = rowbase & 2047;
    u16* hTp = hT + (size_t)sR * 131072;   // [64][2048] per s
#pragma unroll
    for (int r = 0; r < 2; ++r)
#pragma unroll
        for (int c = 0; c < 4; ++c)
            hTp[(size_t)(f0 + c) * 2048 + il + r] = f2bf(acc[r][c]);
    if (fq == 0) {
#pragma unroll
        for (int r = 0; r < 2; ++r) {
            si[rowbase + r] = sip[r];
            sj[rowbase + r] = sjp[r];
        }
    }
}

// ---------------------------------------------------------------------------
// Kernel B: 16 rows/block, 512 threads (8 waves). Phase 1: wave-register
// softmax, 2 rows/wave. Phase 2: split-K MFMA PV — wave wv: f-tile (wv&3),
// K-half (wv>>2); partials combined through a 4 KB LDS buffer.
//   C[f][i] = sum_k hT[f][k] * p[i][k]  via mfma_f32_16x16x32_bf16.
// ---------------------------------------------------------------------------
__global__ __launch_bounds__(512) void k_att(
    const int* __restrict__ adj, const u16* __restrict__ hT,
    const float* __restrict__ si, const float* __restrict__ sj,
    const float* __restrict__ ab_p,
    float* __restrict__ out_h, float* __restrict__ out_att)
{
    __shared__ __align__(16) u16 pB[16 * 2048];   // 64 KB bf16, XOR-swizzled
    __shared__ __align__(16) float red[4][64][4]; // 4 KB split-K partials
    const int t    = threadIdx.x;
    const int lane = t & 63, wv = t >> 6;         // wv 0..7
    const int i0   = blockIdx.x * 16;
    const int s    = i0 >> 11;
    const float ab = ab_p[0];
    const float* sjb = sj + (size_t)s * 2048;

    // sj is shared by all rows of this s -- hoist (32 floats/lane)
    fv4 sv[8];
#pragma unroll
    for (int c = 0; c < 8; ++c)
        sv[c] = *(const fv4*)(sjb + c * 256 + lane * 4);

    // ---- phase 1: 2 rows per wave ----
    for (int rr = 0; rr < 2; ++rr) {
        const int r  = wv * 2 + rr;
        const int fr = i0 + r;
        const float sival = si[fr] + ab;
        const int* arow = adj + (size_t)fr * 2048;
        float v[32];
#pragma unroll
        for (int c = 0; c < 8; ++c) {
            const int j = c * 256 + lane * 4;
            iv4 m = __builtin_nontemporal_load((const iv4*)(arow + j));
            float x;
            x = sival + sv[c].x; x = fmaxf(x, SLOPE * x);
            v[c*4+0] = (m.x == 0 || m.x == -1) ? NEG_INF_F : x;
            x = sival + sv[c].y; x = fmaxf(x, SLOPE * x);
            v[c*4+1] = (m.y == 0 || m.y == -1) ? NEG_INF_F : x;
            x = sival + sv[c].z; x = fmaxf(x, SLOPE * x);
            v[c*4+2] = (m.z == 0 || m.z == -1) ? NEG_INF_F : x;
            x = sival + sv[c].w; x = fmaxf(x, SLOPE * x);
            v[c*4+3] = (m.w == 0 || m.w == -1) ? NEG_INF_F : x;
        }
        float mx = v[0];
#pragma unroll
        for (int q = 1; q < 32; ++q) mx = fmaxf(mx, v[q]);
#pragma unroll
        for (int m2 = 1; m2 < 64; m2 <<= 1) mx = fmaxf(mx, __shfl_xor(mx, m2, 64));
        float sum = 0.f;
#pragma unroll
        for (int q = 0; q < 32; ++q) { v[q] = __expf(v[q] - mx); sum += v[q]; }
#pragma unroll
        for (int m2 = 1; m2 < 64; m2 <<= 1) sum += __shfl_xor(sum, m2, 64);
        const float inv = 1.0f / sum;

        float* attrow = out_att + (size_t)fr * 2048;
        const unsigned swz = (unsigned)(r & 7) << 4;
#pragma unroll
        for (int c = 0; c < 8; ++c) {
            const int j = c * 256 + lane * 4;
            fv4 pv;
            pv.x = v[c*4+0] * inv; pv.y = v[c*4+1] * inv;
            pv.z = v[c*4+2] * inv; pv.w = v[c*4+3] * inv;
            __builtin_nontemporal_store(pv, (fv4*)(attrow + j));
            u16v4 pk;
            pk.x = f2bf(pv.x); pk.y = f2bf(pv.y);
            pk.z = f2bf(pv.z); pk.w = f2bf(pv.w);
            unsigned byte = ((unsigned)(r * 4096 + j * 2)) ^ swz;
            *(u16v4*)((char*)pB + byte) = pk;
        }
    }
    __syncthreads();

    // ---- phase 2: split-K MFMA PV ----
    // Wave wv: f in [(wv&3)*16, +16), i in [i0, i0+16), k in [(wv>>2)*1024, +1024).
    // A-frag: hT[f0 + (lane&15)][kbase + k0 + (lane>>4)*8 + e]
    // B-frag: p[lane&15][kbase + k0 + (lane>>4)*8 + e]   (LDS, swizzled)
    const int fq    = wv & 3;
    const int kh    = wv >> 2;
    const int m16   = lane & 15;
    const int klane = lane >> 4;
    const unsigned sw = (unsigned)(lane & 7) << 4;
    const __bf16* hTs = (const __bf16*)hT + (size_t)s * 131072
                      + (size_t)(fq * 16 + m16) * 2048 + kh * 1024 + klane * 8;
    const unsigned bbase = (unsigned)(m16 * 4096 + kh * 2048 + klane * 16);
    fv4 acc = {0.f, 0.f, 0.f, 0.f};
#pragma unroll 4
    for (int k0 = 0; k0 < 1024; k0 += 32) {
        bf16x8 a = *(const bf16x8*)(hTs + k0);
        unsigned byte = (bbase + (unsigned)(k0 * 2)) ^ sw;
        bf16x8 b = *(const bf16x8*)((const char*)pB + byte);
        acc = __builtin_amdgcn_mfma_f32_16x16x32_bf16(a, b, acc, 0, 0, 0);
    }
    if (kh == 1)
        *(fv4*)&red[fq][lane][0] = acc;
    __syncthreads();
    if (kh == 0) {
        fv4 p2 = *(const fv4*)&red[fq][lane][0];
        acc += p2;
        // C/D layout: col = lane&15 -> i, row = klane*4 + reg -> f
        const int orow = i0 + m16;
        float* op = out_h + (size_t)orow * 64 + fq * 16 + klane * 4;
        fv4 o;
        o.x = fmaxf(acc.x, SLOPE * acc.x);
        o.y = fmaxf(acc.y, SLOPE * acc.y);
        o.z = fmaxf(acc.z, SLOPE * acc.z);
        o.w = fmaxf(acc.w, SLOPE * acc.w);
        *(fv4*)op = o;
    }
}

// ---------------------------------------------------------------------------
extern "C" void kernel_launch(void* const* d_in, const int* in_sizes, int n_in,
                              void* d_out, int out_size, void* d_ws, size_t ws_size,
                              hipStream_t stream) {
    const float* inDoc = (const float*)d_in[0];   // [8][2048][256]
    const int*   adj   = (const int*)d_in[1];     // [8][2048][2048][1]
    const float* W_w   = (const float*)d_in[2];   // [64][256]
    const float* W_b   = (const float*)d_in[3];   // [64]
    const float* a_w   = (const float*)d_in[4];   // [1][128]
    const float* a_b   = (const float*)d_in[5];   // [1]

    float* out     = (float*)d_out;
    float* out_h   = out;                          // 16384*64
    float* out_att = out + (size_t)16384 * 64;     // 8*2048*2048

    float* ws = (float*)d_ws;
    float* wT = ws;                                // 16384 f32
    u16*   hT = (u16*)(ws + 16384);                // 8*64*2048 bf16 = 2 MB
    float* si = (float*)(hT + (size_t)8 * 64 * 2048);
    float* sj = si + 16384;

    k_wt <<<64,   256, 0, stream>>>(W_w, wT);
    k_h  <<<512,  256, 0, stream>>>(inDoc, wT, W_b, a_w, hT, si, sj);
    k_att<<<1024, 512, 0, stream>>>(adj, hT, si, sj, a_b, out_h, out_att);
}

// Round 10
// 95.177 us; speedup vs baseline: 2.3000x; 1.0587x over previous
//
#include <hip/hip_runtime.h>

#define SLOPE 0.1f
#define NEG_INF_F (-9000000000000000.0f)

typedef int            iv4    __attribute__((ext_vector_type(4)));
typedef float          fv4    __attribute__((ext_vector_type(4)));
typedef unsigned short u16;
typedef u16            u16v4  __attribute__((ext_vector_type(4)));
typedef __bf16         bf16x8 __attribute__((ext_vector_type(8)));

static __device__ __forceinline__ u16 f2bf(float x) {
    union { float f; unsigned u; } v; v.f = x;
    unsigned r = v.u + 0x7fffu + ((v.u >> 16) & 1u);   // round-nearest-even
    return (u16)(r >> 16);
}

// Problem constants: S=8, N=2048, IN_F=256, OUT_F=64; rows = 16384.

// ---------------------------------------------------------------------------
// Kernel 0: transpose W_w [64][256] -> wT [256][64] (k-major).
// ---------------------------------------------------------------------------
__global__ void k_wt(const float* __restrict__ W, float* __restrict__ wT) {
    int idx = blockIdx.x * 256 + threadIdx.x;
    int k = idx >> 6, f = idx & 63;
    wT[idx] = W[f * 256 + k];
}

// ---------------------------------------------------------------------------
// Kernel A: h = inDoc @ W^T + b (f32). Outputs: hT bf16 [s][f][i] (PV operand),
// si/sj score vectors. 32-row x 64-f tile per block (512 blocks = 2/CU).
// ---------------------------------------------------------------------------
__global__ __launch_bounds__(256) void k_h(
    const float* __restrict__ inDoc, const float* __restrict__ wT,
    const float* __restrict__ Wb, const float* __restrict__ aw,
    u16* __restrict__ hT, float* __restrict__ si, float* __restrict__ sj)
{
    __shared__ float wTl[32 * 64];      // [k][f], 8 KB
    __shared__ float inl[32][36];       // [r][k], 4.6 KB
    const int t  = threadIdx.x;
    const int R0 = blockIdx.x * 32;
    const int fq = t & 15, rq = t >> 4;
    const int f0 = fq << 2;

    float acc[2][4];
#pragma unroll
    for (int r = 0; r < 2; ++r)
#pragma unroll
        for (int c = 0; c < 4; ++c) acc[r][c] = 0.f;

    for (int kc = 0; kc < 8; ++kc) {
        __syncthreads();
        {   // stage wT chunk [32][64]
            const float4* src = (const float4*)(wT + kc * 2048);
            float4 a = src[t * 2], b = src[t * 2 + 1];
            ((float4*)wTl)[t * 2]     = a;
            ((float4*)wTl)[t * 2 + 1] = b;
        }
        {   // stage inDoc chunk [32 rows][32 k]
            int r = t >> 3, q = t & 7;
            const float* src = inDoc + (size_t)(R0 + r) * 256 + kc * 32 + q * 4;
            *(float4*)&inl[r][q * 4] = *(const float4*)src;
        }
        __syncthreads();
#pragma unroll
        for (int k4 = 0; k4 < 8; ++k4) {
            const int k0 = k4 << 2;
            float w[4][4];
#pragma unroll
            for (int j = 0; j < 4; ++j) {
                float4 wv = *(const float4*)&wTl[(k0 + j) * 64 + f0];
                w[j][0] = wv.x; w[j][1] = wv.y; w[j][2] = wv.z; w[j][3] = wv.w;
            }
#pragma unroll
            for (int r = 0; r < 2; ++r) {
                float4 av = *(const float4*)&inl[rq * 2 + r][k0];
                float a[4] = {av.x, av.y, av.z, av.w};
#pragma unroll
                for (int j = 0; j < 4; ++j)
#pragma unroll
                    for (int c = 0; c < 4; ++c)
                        acc[r][c] = fmaf(a[j], w[j][c], acc[r][c]);
            }
        }
    }

    float bw[4], a1[4], a2[4];
#pragma unroll
    for (int c = 0; c < 4; ++c) {
        bw[c] = Wb[f0 + c];
        a1[c] = aw[f0 + c];
        a2[c] = aw[64 + f0 + c];
    }
    float sip[2], sjp[2];
#pragma unroll
    for (int r = 0; r < 2; ++r) {
#pragma unroll
        for (int c = 0; c < 4; ++c) acc[r][c] += bw[c];
        float x = 0.f, y = 0.f;
#pragma unroll
        for (int c = 0; c < 4; ++c) {
            x = fmaf(acc[r][c], a1[c], x);
            y = fmaf(acc[r][c], a2[c], y);
        }
        sip[r] = x; sjp[r] = y;
    }
#pragma unroll
    for (int m = 1; m <= 8; m <<= 1) {
#pragma unroll
        for (int r = 0; r < 2; ++r) {
            sip[r] += __shfl_xor(sip[r], m, 64);
            sjp[r] += __shfl_xor(sjp[r], m, 64);
        }
    }
    const int rowbase = R0 + rq * 2;
    const int sR = rowbase >> 11;
    const int il = rowbase & 2047;
    u16* hTp = hT + (size_t)sR * 131072;   // [64][2048] per s
#pragma unroll
    for (int r = 0; r < 2; ++r)
#pragma unroll
        for (int c = 0; c < 4; ++c)
            hTp[(size_t)(f0 + c) * 2048 + il + r] = f2bf(acc[r][c]);
    if (fq == 0) {
#pragma unroll
        for (int r = 0; r < 2; ++r) {
            si[rowbase + r] = sip[r];
            sj[rowbase + r] = sjp[r];
        }
    }
}

// ---------------------------------------------------------------------------
// Kernel B: 16 rows/block, 512 threads (8 waves). Phase 1: 2 rows/wave with
// ALL 16 adj loads issued up front (MLP), then both softmaxes.
// Phase 2: split-K MFMA PV (wave wv: f-tile wv&3, K-half wv>>2), partials
// combined through a 4 KB LDS buffer.
// ---------------------------------------------------------------------------
__global__ __launch_bounds__(512, 2) void k_att(
    const int* __restrict__ adj, const u16* __restrict__ hT,
    const float* __restrict__ si, const float* __restrict__ sj,
    const float* __restrict__ ab_p,
    float* __restrict__ out_h, float* __restrict__ out_att)
{
    __shared__ __align__(16) u16 pB[16 * 2048];   // 64 KB bf16, XOR-swizzled
    __shared__ __align__(16) float red[4][64][4]; // 4 KB split-K partials
    const int t    = threadIdx.x;
    const int lane = t & 63, wv = t >> 6;         // wv 0..7
    const int i0   = blockIdx.x * 16;
    const int s    = i0 >> 11;
    const float ab = ab_p[0];
    const float* sjb = sj + (size_t)s * 2048;

    // sj is shared by all rows of this s -- hoist (32 floats/lane)
    fv4 sv[8];
#pragma unroll
    for (int c = 0; c < 8; ++c)
        sv[c] = *(const fv4*)(sjb + c * 256 + lane * 4);

    // ---- phase 1: 2 rows/wave, all 16 adj loads in flight first ----
    const int r0  = wv * 2,      r1  = r0 + 1;
    const int fr0 = i0 + r0,     fr1 = i0 + r1;
    const float si0 = si[fr0] + ab;
    const float si1 = si[fr1] + ab;
    const int* a0 = adj + (size_t)fr0 * 2048;
    const int* a1 = adj + (size_t)fr1 * 2048;

    iv4 m0[8], m1[8];
#pragma unroll
    for (int c = 0; c < 8; ++c)
        m0[c] = __builtin_nontemporal_load((const iv4*)(a0 + c * 256 + lane * 4));
#pragma unroll
    for (int c = 0; c < 8; ++c)
        m1[c] = __builtin_nontemporal_load((const iv4*)(a1 + c * 256 + lane * 4));

#pragma unroll
    for (int rr = 0; rr < 2; ++rr) {
        const int r  = rr ? r1 : r0;
        const int fr = rr ? fr1 : fr0;
        const float sival = rr ? si1 : si0;
        iv4* mm = rr ? m1 : m0;
        float v[32];
#pragma unroll
        for (int c = 0; c < 8; ++c) {
            iv4 m = mm[c];
            float x;
            x = sival + sv[c].x; x = fmaxf(x, SLOPE * x);
            v[c*4+0] = (m.x == 0 || m.x == -1) ? NEG_INF_F : x;
            x = sival + sv[c].y; x = fmaxf(x, SLOPE * x);
            v[c*4+1] = (m.y == 0 || m.y == -1) ? NEG_INF_F : x;
            x = sival + sv[c].z; x = fmaxf(x, SLOPE * x);
            v[c*4+2] = (m.z == 0 || m.z == -1) ? NEG_INF_F : x;
            x = sival + sv[c].w; x = fmaxf(x, SLOPE * x);
            v[c*4+3] = (m.w == 0 || m.w == -1) ? NEG_INF_F : x;
        }
        float mx = v[0];
#pragma unroll
        for (int q = 1; q < 32; ++q) mx = fmaxf(mx, v[q]);
#pragma unroll
        for (int m2 = 1; m2 < 64; m2 <<= 1) mx = fmaxf(mx, __shfl_xor(mx, m2, 64));
        float sum = 0.f;
#pragma unroll
        for (int q = 0; q < 32; ++q) { v[q] = __expf(v[q] - mx); sum += v[q]; }
#pragma unroll
        for (int m2 = 1; m2 < 64; m2 <<= 1) sum += __shfl_xor(sum, m2, 64);
        const float inv = 1.0f / sum;

        float* attrow = out_att + (size_t)fr * 2048;
        const unsigned swz = (unsigned)(r & 7) << 4;
#pragma unroll
        for (int c = 0; c < 8; ++c) {
            const int j = c * 256 + lane * 4;
            fv4 pv;
            pv.x = v[c*4+0] * inv; pv.y = v[c*4+1] * inv;
            pv.z = v[c*4+2] * inv; pv.w = v[c*4+3] * inv;
            __builtin_nontemporal_store(pv, (fv4*)(attrow + j));
            u16v4 pk;
            pk.x = f2bf(pv.x); pk.y = f2bf(pv.y);
            pk.z = f2bf(pv.z); pk.w = f2bf(pv.w);
            unsigned byte = ((unsigned)(r * 4096 + j * 2)) ^ swz;
            *(u16v4*)((char*)pB + byte) = pk;
        }
    }
    __syncthreads();

    // ---- phase 2: split-K MFMA PV ----
    // Wave wv: f in [(wv&3)*16, +16), i in [i0, i0+16), k in [(wv>>2)*1024, +1024).
    const int fq    = wv & 3;
    const int kh    = wv >> 2;
    const int m16   = lane & 15;
    const int klane = lane >> 4;
    const unsigned sw = (unsigned)(lane & 7) << 4;
    const __bf16* hTs = (const __bf16*)hT + (size_t)s * 131072
                      + (size_t)(fq * 16 + m16) * 2048 + kh * 1024 + klane * 8;
    const unsigned bbase = (unsigned)(m16 * 4096 + kh * 2048 + klane * 16);
    fv4 acc = {0.f, 0.f, 0.f, 0.f};
#pragma unroll 4
    for (int k0 = 0; k0 < 1024; k0 += 32) {
        bf16x8 a = *(const bf16x8*)(hTs + k0);
        unsigned byte = (bbase + (unsigned)(k0 * 2)) ^ sw;
        bf16x8 b = *(const bf16x8*)((const char*)pB + byte);
        acc = __builtin_amdgcn_mfma_f32_16x16x32_bf16(a, b, acc, 0, 0, 0);
    }
    if (kh == 1)
        *(fv4*)&red[fq][lane][0] = acc;
    __syncthreads();
    if (kh == 0) {
        fv4 p2 = *(const fv4*)&red[fq][lane][0];
        acc += p2;
        // C/D layout: col = lane&15 -> i, row = klane*4 + reg -> f
        const int orow = i0 + m16;
        float* op = out_h + (size_t)orow * 64 + fq * 16 + klane * 4;
        fv4 o;
        o.x = fmaxf(acc.x, SLOPE * acc.x);
        o.y = fmaxf(acc.y, SLOPE * acc.y);
        o.z = fmaxf(acc.z, SLOPE * acc.z);
        o.w = fmaxf(acc.w, SLOPE * acc.w);
        *(fv4*)op = o;
    }
}

// ---------------------------------------------------------------------------
extern "C" void kernel_launch(void* const* d_in, const int* in_sizes, int n_in,
                              void* d_out, int out_size, void* d_ws, size_t ws_size,
                              hipStream_t stream) {
    const float* inDoc = (const float*)d_in[0];   // [8][2048][256]
    const int*   adj   = (const int*)d_in[1];     // [8][2048][2048][1]
    const float* W_w   = (const float*)d_in[2];   // [64][256]
    const float* W_b   = (const float*)d_in[3];   // [64]
    const float* a_w   = (const float*)d_in[4];   // [1][128]
    const float* a_b   = (const float*)d_in[5];   // [1]

    float* out     = (float*)d_out;
    float* out_h   = out;                          // 16384*64
    float* out_att = out + (size_t)16384 * 64;     // 8*2048*2048

    float* ws = (float*)d_ws;
    float* wT = ws;                                // 16384 f32
    u16*   hT = (u16*)(ws + 16384);                // 8*64*2048 bf16 = 2 MB
    float* si = (float*)(hT + (size_t)8 * 64 * 2048);
    float* sj = si + 16384;

    k_wt <<<64,   256, 0, stream>>>(W_w, wT);
    k_h  <<<512,  256, 0, stream>>>(inDoc, wT, W_b, a_w, hT, si, sj);
    k_att<<<1024, 512, 0, stream>>>(adj, hT, si, sj, a_b, out_h, out_att);
}

// Round 11
// 91.079 us; speedup vs baseline: 2.4035x; 1.0450x over previous
//
#include <hip/hip_runtime.h>

#define SLOPE 0.1f
#define NEG_INF_F (-9000000000000000.0f)

typedef int            iv4    __attribute__((ext_vector_type(4)));
typedef float          fv4    __attribute__((ext_vector_type(4)));
typedef unsigned short u16;
typedef u16            u16v4  __attribute__((ext_vector_type(4)));
typedef __bf16         bf16x8 __attribute__((ext_vector_type(8)));

static __device__ __forceinline__ u16 f2bf(float x) {
    union { float f; unsigned u; } v; v.f = x;
    unsigned r = v.u + 0x7fffu + ((v.u >> 16) & 1u);   // round-nearest-even
    return (u16)(r >> 16);
}

// LDS-only barrier: wait for this wave's LDS ops, then s_barrier, WITHOUT
// draining outstanding global stores (the compiler's __syncthreads emits
// s_waitcnt vmcnt(0) which stalls on NT store acks).
static __device__ __forceinline__ void lds_barrier() {
    asm volatile("s_waitcnt lgkmcnt(0)" ::: "memory");
    __builtin_amdgcn_s_barrier();
}

// Problem constants: S=8, N=2048, IN_F=256, OUT_F=64; rows = 16384.

// ---------------------------------------------------------------------------
// Kernel 0: transpose W_w [64][256] -> wT [256][64] (k-major).
// ---------------------------------------------------------------------------
__global__ void k_wt(const float* __restrict__ W, float* __restrict__ wT) {
    int idx = blockIdx.x * 256 + threadIdx.x;
    int k = idx >> 6, f = idx & 63;
    wT[idx] = W[f * 256 + k];
}

// ---------------------------------------------------------------------------
// Kernel A: h = inDoc @ W^T + b (f32). Outputs: hT bf16 [s][f][i] (PV operand),
// si/sj score vectors. 32-row x 64-f tile per block (512 blocks = 2/CU).
// ---------------------------------------------------------------------------
__global__ __launch_bounds__(256) void k_h(
    const float* __restrict__ inDoc, const float* __restrict__ wT,
    const float* __restrict__ Wb, const float* __restrict__ aw,
    u16* __restrict__ hT, float* __restrict__ si, float* __restrict__ sj)
{
    __shared__ float wTl[32 * 64];      // [k][f], 8 KB
    __shared__ float inl[32][36];       // [r][k], 4.6 KB
    const int t  = threadIdx.x;
    const int R0 = blockIdx.x * 32;
    const int fq = t & 15, rq = t >> 4;
    const int f0 = fq << 2;

    float acc[2][4];
#pragma unroll
    for (int r = 0; r < 2; ++r)
#pragma unroll
        for (int c = 0; c < 4; ++c) acc[r][c] = 0.f;

    for (int kc = 0; kc < 8; ++kc) {
        __syncthreads();
        {   // stage wT chunk [32][64]
            const float4* src = (const float4*)(wT + kc * 2048);
            float4 a = src[t * 2], b = src[t * 2 + 1];
            ((float4*)wTl)[t * 2]     = a;
            ((float4*)wTl)[t * 2 + 1] = b;
        }
        {   // stage inDoc chunk [32 rows][32 k]
            int r = t >> 3, q = t & 7;
            const float* src = inDoc + (size_t)(R0 + r) * 256 + kc * 32 + q * 4;
            *(float4*)&inl[r][q * 4] = *(const float4*)src;
        }
        __syncthreads();
#pragma unroll
        for (int k4 = 0; k4 < 8; ++k4) {
            const int k0 = k4 << 2;
            float w[4][4];
#pragma unroll
            for (int j = 0; j < 4; ++j) {
                float4 wv = *(const float4*)&wTl[(k0 + j) * 64 + f0];
                w[j][0] = wv.x; w[j][1] = wv.y; w[j][2] = wv.z; w[j][3] = wv.w;
            }
#pragma unroll
            for (int r = 0; r < 2; ++r) {
                float4 av = *(const float4*)&inl[rq * 2 + r][k0];
                float a[4] = {av.x, av.y, av.z, av.w};
#pragma unroll
                for (int j = 0; j < 4; ++j)
#pragma unroll
                    for (int c = 0; c < 4; ++c)
                        acc[r][c] = fmaf(a[j], w[j][c], acc[r][c]);
            }
        }
    }

    float bw[4], a1[4], a2[4];
#pragma unroll
    for (int c = 0; c < 4; ++c) {
        bw[c] = Wb[f0 + c];
        a1[c] = aw[f0 + c];
        a2[c] = aw[64 + f0 + c];
    }
    float sip[2], sjp[2];
#pragma unroll
    for (int r = 0; r < 2; ++r) {
#pragma unroll
        for (int c = 0; c < 4; ++c) acc[r][c] += bw[c];
        float x = 0.f, y = 0.f;
#pragma unroll
        for (int c = 0; c < 4; ++c) {
            x = fmaf(acc[r][c], a1[c], x);
            y = fmaf(acc[r][c], a2[c], y);
        }
        sip[r] = x; sjp[r] = y;
    }
#pragma unroll
    for (int m = 1; m <= 8; m <<= 1) {
#pragma unroll
        for (int r = 0; r < 2; ++r) {
            sip[r] += __shfl_xor(sip[r], m, 64);
            sjp[r] += __shfl_xor(sjp[r], m, 64);
        }
    }
    const int rowbase = R0 + rq * 2;
    const int sR = rowbase >> 11;
    const int il = rowbase & 2047;
    u16* hTp = hT + (size_t)sR * 131072;   // [64][2048] per s
#pragma unroll
    for (int r = 0; r < 2; ++r)
#pragma unroll
        for (int c = 0; c < 4; ++c)
            hTp[(size_t)(f0 + c) * 2048 + il + r] = f2bf(acc[r][c]);
    if (fq == 0) {
#pragma unroll
        for (int r = 0; r < 2; ++r) {
            si[rowbase + r] = sip[r];
            sj[rowbase + r] = sjp[r];
        }
    }
}

// ---------------------------------------------------------------------------
// Kernel B: 16 rows/block, 512 threads (8 waves). Phase 1: 2 rows/wave,
// all 16 adj loads up front (MLP), cached att stores. Phase 2: split-K
// MFMA PV behind an LDS-only barrier (att stores drain under the MFMAs).
// ---------------------------------------------------------------------------
__global__ __launch_bounds__(512, 2) void k_att(
    const int* __restrict__ adj, const u16* __restrict__ hT,
    const float* __restrict__ si, const float* __restrict__ sj,
    const float* __restrict__ ab_p,
    float* __restrict__ out_h, float* __restrict__ out_att)
{
    __shared__ __align__(16) u16 pB[16 * 2048];   // 64 KB bf16, XOR-swizzled
    __shared__ __align__(16) float red[4][64][4]; // 4 KB split-K partials
    const int t    = threadIdx.x;
    const int lane = t & 63, wv = t >> 6;         // wv 0..7
    const int i0   = blockIdx.x * 16;
    const int s    = i0 >> 11;
    const float ab = ab_p[0];
    const float* sjb = sj + (size_t)s * 2048;

    // sj is shared by all rows of this s -- hoist (32 floats/lane)
    fv4 sv[8];
#pragma unroll
    for (int c = 0; c < 8; ++c)
        sv[c] = *(const fv4*)(sjb + c * 256 + lane * 4);

    // ---- phase 1: 2 rows/wave, all 16 adj loads in flight first ----
    const int r0  = wv * 2,      r1  = r0 + 1;
    const int fr0 = i0 + r0,     fr1 = i0 + r1;
    const float si0 = si[fr0] + ab;
    const float si1 = si[fr1] + ab;
    const int* a0 = adj + (size_t)fr0 * 2048;
    const int* a1 = adj + (size_t)fr1 * 2048;

    iv4 m0[8], m1[8];
#pragma unroll
    for (int c = 0; c < 8; ++c)
        m0[c] = __builtin_nontemporal_load((const iv4*)(a0 + c * 256 + lane * 4));
#pragma unroll
    for (int c = 0; c < 8; ++c)
        m1[c] = __builtin_nontemporal_load((const iv4*)(a1 + c * 256 + lane * 4));

#pragma unroll
    for (int rr = 0; rr < 2; ++rr) {
        const int r  = rr ? r1 : r0;
        const int fr = rr ? fr1 : fr0;
        const float sival = rr ? si1 : si0;
        iv4* mm = rr ? m1 : m0;
        float v[32];
#pragma unroll
        for (int c = 0; c < 8; ++c) {
            iv4 m = mm[c];
            float x;
            x = sival + sv[c].x; x = fmaxf(x, SLOPE * x);
            v[c*4+0] = (m.x == 0 || m.x == -1) ? NEG_INF_F : x;
            x = sival + sv[c].y; x = fmaxf(x, SLOPE * x);
            v[c*4+1] = (m.y == 0 || m.y == -1) ? NEG_INF_F : x;
            x = sival + sv[c].z; x = fmaxf(x, SLOPE * x);
            v[c*4+2] = (m.z == 0 || m.z == -1) ? NEG_INF_F : x;
            x = sival + sv[c].w; x = fmaxf(x, SLOPE * x);
            v[c*4+3] = (m.w == 0 || m.w == -1) ? NEG_INF_F : x;
        }
        float mx = v[0];
#pragma unroll
        for (int q = 1; q < 32; ++q) mx = fmaxf(mx, v[q]);
#pragma unroll
        for (int m2 = 1; m2 < 64; m2 <<= 1) mx = fmaxf(mx, __shfl_xor(mx, m2, 64));
        float sum = 0.f;
#pragma unroll
        for (int q = 0; q < 32; ++q) { v[q] = __expf(v[q] - mx); sum += v[q]; }
#pragma unroll
        for (int m2 = 1; m2 < 64; m2 <<= 1) sum += __shfl_xor(sum, m2, 64);
        const float inv = 1.0f / sum;

        float* attrow = out_att + (size_t)fr * 2048;
        const unsigned swz = (unsigned)(r & 7) << 4;
#pragma unroll
        for (int c = 0; c < 8; ++c) {
            const int j = c * 256 + lane * 4;
            fv4 pv;
            pv.x = v[c*4+0] * inv; pv.y = v[c*4+1] * inv;
            pv.z = v[c*4+2] * inv; pv.w = v[c*4+3] * inv;
            *(fv4*)(attrow + j) = pv;            // cached store; drains under MFMA
            u16v4 pk;
            pk.x = f2bf(pv.x); pk.y = f2bf(pv.y);
            pk.z = f2bf(pv.z); pk.w = f2bf(pv.w);
            unsigned byte = ((unsigned)(r * 4096 + j * 2)) ^ swz;
            *(u16v4*)((char*)pB + byte) = pk;
        }
    }
    lds_barrier();   // wait LDS writes only -- NOT the att global stores

    // ---- phase 2: split-K MFMA PV ----
    // Wave wv: f in [(wv&3)*16, +16), i in [i0, i0+16), k in [(wv>>2)*1024, +1024).
    const int fq    = wv & 3;
    const int kh    = wv >> 2;
    const int m16   = lane & 15;
    const int klane = lane >> 4;
    const unsigned sw = (unsigned)(lane & 7) << 4;
    const __bf16* hTs = (const __bf16*)hT + (size_t)s * 131072
                      + (size_t)(fq * 16 + m16) * 2048 + kh * 1024 + klane * 8;
    const unsigned bbase = (unsigned)(m16 * 4096 + kh * 2048 + klane * 16);
    fv4 acc = {0.f, 0.f, 0.f, 0.f};
#pragma unroll 4
    for (int k0 = 0; k0 < 1024; k0 += 32) {
        bf16x8 a = *(const bf16x8*)(hTs + k0);
        unsigned byte = (bbase + (unsigned)(k0 * 2)) ^ sw;
        bf16x8 b = *(const bf16x8*)((const char*)pB + byte);
        acc = __builtin_amdgcn_mfma_f32_16x16x32_bf16(a, b, acc, 0, 0, 0);
    }
    if (kh == 1)
        *(fv4*)&red[fq][lane][0] = acc;
    lds_barrier();
    if (kh == 0) {
        fv4 p2 = *(const fv4*)&red[fq][lane][0];
        acc += p2;
        // C/D layout: col = lane&15 -> i, row = klane*4 + reg -> f
        const int orow = i0 + m16;
        float* op = out_h + (size_t)orow * 64 + fq * 16 + klane * 4;
        fv4 o;
        o.x = fmaxf(acc.x, SLOPE * acc.x);
        o.y = fmaxf(acc.y, SLOPE * acc.y);
        o.z = fmaxf(acc.z, SLOPE * acc.z);
        o.w = fmaxf(acc.w, SLOPE * acc.w);
        *(fv4*)op = o;
    }
}

// ---------------------------------------------------------------------------
extern "C" void kernel_launch(void* const* d_in, const int* in_sizes, int n_in,
                              void* d_out, int out_size, void* d_ws, size_t ws_size,
                              hipStream_t stream) {
    const float* inDoc = (const float*)d_in[0];   // [8][2048][256]
    const int*   adj   = (const int*)d_in[1];     // [8][2048][2048][1]
    const float* W_w   = (const float*)d_in[2];   // [64][256]
    const float* W_b   = (const float*)d_in[3];   // [64]
    const float* a_w   = (const float*)d_in[4];   // [1][128]
    const float* a_b   = (const float*)d_in[5];   // [1]

    float* out     = (float*)d_out;
    float* out_h   = out;                          // 16384*64
    float* out_att = out + (size_t)16384 * 64;     // 8*2048*2048

    float* ws = (float*)d_ws;
    float* wT = ws;                                // 16384 f32
    u16*   hT = (u16*)(ws + 16384);                // 8*64*2048 bf16 = 2 MB
    float* si = (float*)(hT + (size_t)8 * 64 * 2048);
    float* sj = si + 16384;

    k_wt <<<64,   256, 0, stream>>>(W_w, wT);
    k_h  <<<512,  256, 0, stream>>>(inDoc, wT, W_b, a_w, hT, si, sj);
    k_att<<<1024, 512, 0, stream>>>(adj, hT, si, sj, a_b, out_h, out_att);
}